// Round 2
// baseline (4014.075 us; speedup 1.0000x reference)
//
#include <hip/hip_runtime.h>

typedef unsigned short u16;
typedef unsigned int   u32;
typedef __bf16  bf16x8 __attribute__((ext_vector_type(8)));
typedef float   f32x4  __attribute__((ext_vector_type(4)));

#define B_   16
#define S_   512
#define H_   768
#define NH_  12
#define L_   6
#define FF_  3072
#define M_   8192     // B_*S_
#define LAB_ 10

// ---------- bf16 helpers (storage = u16 bits) ----------
__device__ __forceinline__ float b2f(u16 x) {
    u32 u = ((u32)x) << 16; float f; __builtin_memcpy(&f, &u, 4); return f;
}
__device__ __forceinline__ u16 f2b(float f) {
    u32 u; __builtin_memcpy(&u, &f, 4);
    u32 r = u + 0x7FFFu + ((u >> 16) & 1u);
    return (u16)(r >> 16);
}
__device__ __forceinline__ void up2(u32 u, float& a, float& b) {
    u32 lo = u << 16, hi = u & 0xFFFF0000u;
    __builtin_memcpy(&a, &lo, 4); __builtin_memcpy(&b, &hi, 4);
}
// dtype-dispatched load of a float input: bf=1 -> bf16 storage, bf=0 -> fp32 storage
__device__ __forceinline__ float lda(const void* p, size_t i, int bf) {
    return bf ? b2f(((const u16*)p)[i]) : ((const float*)p)[i];
}
__device__ __forceinline__ float gelu_tanh(float x) {
    return 0.5f * x * (1.0f + tanhf(0.7978845608028654f * (x + 0.044715f * x * x * x)));
}

// ---------- dtype detect: emb_ln_g is all ones ----------
__global__ void detect_kernel(const u32* __restrict__ g, int* __restrict__ flag) {
    // fp32 ones -> 0x3F800000 ; bf16 ones pair -> 0x3F803F80
    flag[0] = (g[0] == 0x3F803F80u) ? 1 : 0;
}

// ---------- block reduce (sum of two values), 256 threads ----------
__device__ __forceinline__ void block_reduce2(float& s, float& s2, float* red, int tid) {
    int lane = tid & 63, wave = tid >> 6;
    #pragma unroll
    for (int m = 32; m >= 1; m >>= 1) { s += __shfl_xor(s, m); s2 += __shfl_xor(s2, m); }
    if (lane == 0) { red[wave] = s; red[4 + wave] = s2; }
    __syncthreads();
    s  = red[0] + red[1] + red[2] + red[3];
    s2 = red[4] + red[5] + red[6] + red[7];
}

// ---------- weight transpose+convert: in (K x N, f32 or bf16) -> out bf16 (N x K) ----------
__global__ __launch_bounds__(256) void transpose_k(const void* __restrict__ in,
                                                   u16* __restrict__ out, int K, int N,
                                                   const int* __restrict__ fl) {
    __shared__ u16 tile[64][65];
    const int bf = fl[0];
    const size_t moff = (size_t)blockIdx.z * (size_t)K * (size_t)N;
    int k0 = blockIdx.y * 64, n0 = blockIdx.x * 64;
    int c = threadIdx.x & 63, r0 = threadIdx.x >> 6;
    #pragma unroll
    for (int r = r0; r < 64; r += 4) {
        size_t idx = moff + (size_t)(k0 + r) * N + n0 + c;
        tile[r][c] = bf ? ((const u16*)in)[idx] : f2b(((const float*)in)[idx]);
    }
    __syncthreads();
    #pragma unroll
    for (int r = r0; r < 64; r += 4)
        out[moff + (size_t)(n0 + r) * K + k0 + c] = tile[c][r];
}

// ---------- embedding + LN + selection scale ----------
__global__ __launch_bounds__(256) void embed_kernel(
    const int* __restrict__ src, const int* __restrict__ seg, const int* __restrict__ tib,
    const void* __restrict__ we, const void* __restrict__ pe, const void* __restrict__ se,
    const void* __restrict__ g, const void* __restrict__ bb, const void* __restrict__ sf,
    float* __restrict__ x32, u16* __restrict__ xb, const int* __restrict__ fl) {
    __shared__ float red[8];
    const int bf = fl[0];
    const int r = blockIdx.x, tid = threadIdx.x;
    const int s = r & (S_ - 1);
    const int w = src[r], sg = seg[r];
    const float scale = lda(sf, tib[r], bf);
    float v[3]; int col[3];
    #pragma unroll
    for (int i = 0; i < 3; ++i) {
        col[i] = tid + i * 256;
        v[i] = lda(we, (size_t)w * H_ + col[i], bf) + lda(pe, (size_t)s * H_ + col[i], bf)
             + lda(se, (size_t)sg * H_ + col[i], bf);
    }
    float su = v[0] + v[1] + v[2];
    float sq = v[0]*v[0] + v[1]*v[1] + v[2]*v[2];
    block_reduce2(su, sq, red, tid);
    const float mean = su * (1.0f / H_);
    const float var  = sq * (1.0f / H_) - mean * mean;
    const float inv  = rsqrtf(var + 1e-5f);
    #pragma unroll
    for (int i = 0; i < 3; ++i) {
        float y = ((v[i] - mean) * inv * lda(g, col[i], bf) + lda(bb, col[i], bf)) * scale;
        x32[(size_t)r * H_ + col[i]] = y;
        xb [(size_t)r * H_ + col[i]] = f2b(y);
    }
}

// ---------- residual add + LN (x32 in-place master, bf16 shadow out) ----------
__global__ __launch_bounds__(256) void add_ln_kernel(
    const float* __restrict__ xin, const u16* __restrict__ t,
    const void* __restrict__ g, const void* __restrict__ bb, long goff,
    float* __restrict__ xout, u16* __restrict__ xb, const int* __restrict__ fl) {
    __shared__ float red[8];
    const int bf = fl[0];
    const int r = blockIdx.x, tid = threadIdx.x;
    const size_t rb = (size_t)r * H_;
    float v[3]; int col[3];
    #pragma unroll
    for (int i = 0; i < 3; ++i) {
        col[i] = tid + i * 256;
        v[i] = xin[rb + col[i]] + b2f(t[rb + col[i]]);
    }
    float su = v[0] + v[1] + v[2];
    float sq = v[0]*v[0] + v[1]*v[1] + v[2]*v[2];
    block_reduce2(su, sq, red, tid);
    const float mean = su * (1.0f / H_);
    const float var  = sq * (1.0f / H_) - mean * mean;
    const float inv  = rsqrtf(var + 1e-5f);
    #pragma unroll
    for (int i = 0; i < 3; ++i) {
        float y = (v[i] - mean) * inv * lda(g, goff + col[i], bf) + lda(bb, goff + col[i], bf);
        xout[rb + col[i]] = y;
        xb  [rb + col[i]] = f2b(y);
    }
}

// ---------- MFMA GEMM: C[M,N] = A[M,K] * Bt[N,K]^T + bias, act: 0=none 1=gelu ----------
__global__ __launch_bounds__(256) void gemm_bt(
    const u16* __restrict__ A, const u16* __restrict__ Bt,
    const void* __restrict__ bias, long bias_off,
    u16* __restrict__ C, int M, int N, int K, int act, const int* __restrict__ fl) {
    __shared__ alignas(16) u16 As[128 * 32];
    __shared__ alignas(16) u16 Bs[128 * 32];
    const int bf = fl[0];
    const int tid = threadIdx.x;
    const int bm = blockIdx.y * 128, bn = blockIdx.x * 128;
    const int wave = tid >> 6, lane = tid & 63;
    const int wm = (wave >> 1) * 64, wn = (wave & 1) * 64;
    const int qd = lane >> 4, l16 = lane & 15;

    const f32x4 fz = {0.f, 0.f, 0.f, 0.f};
    f32x4 acc[4][4];
    #pragma unroll
    for (int i = 0; i < 4; ++i)
        #pragma unroll
        for (int j = 0; j < 4; ++j) acc[i][j] = fz;

    const int c0 = tid, c1 = tid + 256;
    const int r0 = c0 >> 2, cc0 = (c0 & 3) * 8;
    const int r1 = c1 >> 2, cc1 = (c1 & 3) * 8;
    const u16* A0 = A  + (size_t)(bm + r0) * K + cc0;
    const u16* A1 = A  + (size_t)(bm + r1) * K + cc1;
    const u16* B0 = Bt + (size_t)(bn + r0) * K + cc0;
    const u16* B1 = Bt + (size_t)(bn + r1) * K + cc1;

    for (int k0 = 0; k0 < K; k0 += 32) {
        uint4 a0 = *(const uint4*)(A0 + k0);
        uint4 a1 = *(const uint4*)(A1 + k0);
        uint4 b0 = *(const uint4*)(B0 + k0);
        uint4 b1 = *(const uint4*)(B1 + k0);
        __syncthreads();               // previous iter's LDS reads complete
        *(uint4*)(As + c0 * 8) = a0;
        *(uint4*)(As + c1 * 8) = a1;
        *(uint4*)(Bs + c0 * 8) = b0;
        *(uint4*)(Bs + c1 * 8) = b1;
        __syncthreads();
        bf16x8 af[4], bfv[4];
        #pragma unroll
        for (int i = 0; i < 4; ++i)
            af[i] = *(const bf16x8*)(As + (wm + i * 16 + l16) * 32 + qd * 8);
        #pragma unroll
        for (int j = 0; j < 4; ++j)
            bfv[j] = *(const bf16x8*)(Bs + (wn + j * 16 + l16) * 32 + qd * 8);
        #pragma unroll
        for (int i = 0; i < 4; ++i)
            #pragma unroll
            for (int j = 0; j < 4; ++j)
                acc[i][j] = __builtin_amdgcn_mfma_f32_16x16x32_bf16(af[i], bfv[j], acc[i][j], 0, 0, 0);
    }

    // epilogue: C/D layout col=lane&15, row=(lane>>4)*4+reg
    #pragma unroll
    for (int i = 0; i < 4; ++i) {
        const int row0 = bm + wm + i * 16 + qd * 4;
        #pragma unroll
        for (int j = 0; j < 4; ++j) {
            const int col = bn + wn + j * 16 + l16;
            const float bv = lda(bias, bias_off + col, bf);
            #pragma unroll
            for (int r = 0; r < 4; ++r) {
                float v = acc[i][j][r] + bv;
                if (act == 1) v = gelu_tanh(v);
                C[(size_t)(row0 + r) * N + col] = f2b(v);
            }
        }
    }
}

// ---------- attention: per (qtile of 32, head, batch). MFMA QK^T, softmax, VALU PV ----------
__global__ __launch_bounds__(256) void attn_kernel(
    const u16* __restrict__ Qb, const u16* __restrict__ Kb, const u16* __restrict__ Vb,
    const int* __restrict__ seg, u16* __restrict__ Cb) {
    __shared__ alignas(16) u16 sc16[32 * 520];   // scores -> probs (bf16), row stride 520
    __shared__ alignas(16) u16 Qs[32 * 72];
    __shared__ alignas(16) u16 Ks[128 * 72];
    __shared__ float biasv[512];
    const int tid = threadIdx.x;
    const int qt = blockIdx.x, h = blockIdx.y, b = blockIdx.z;
    const int lane = tid & 63, wave = tid >> 6;
    const int qd = lane >> 4, l16 = lane & 15;
    const size_t base = ((size_t)b * S_) * H_ + h * 64;

    for (int i = tid; i < 512; i += 256)
        biasv[i] = (seg[b * S_ + i] > 0) ? 0.0f : -1e9f;
    {   // stage Q tile 32x64
        int c = tid, r = c >> 3, c8 = (c & 7) * 8;
        uint4 v4 = *(const uint4*)(Qb + base + (size_t)(qt * 32 + r) * H_ + c8);
        *(uint4*)(Qs + r * 72 + c8) = v4;
    }
    __syncthreads();

    // ---- scores via MFMA, 4 key-tiles of 128 ----
    const f32x4 fz = {0.f, 0.f, 0.f, 0.f};
    for (int kt = 0; kt < 512; kt += 128) {
        #pragma unroll
        for (int i = 0; i < 4; ++i) {
            int c = tid + i * 256;
            int r = c >> 3, c8 = (c & 7) * 8;
            uint4 v4 = *(const uint4*)(Kb + base + (size_t)(kt + r) * H_ + c8);
            *(uint4*)(Ks + r * 72 + c8) = v4;
        }
        __syncthreads();
        f32x4 acc[2][2];
        acc[0][0] = fz; acc[0][1] = fz; acc[1][0] = fz; acc[1][1] = fz;
        #pragma unroll
        for (int kd = 0; kd < 2; ++kd) {
            bf16x8 af[2], bk[2];
            #pragma unroll
            for (int mt = 0; mt < 2; ++mt)
                af[mt] = *(const bf16x8*)(Qs + (mt * 16 + l16) * 72 + kd * 32 + qd * 8);
            #pragma unroll
            for (int nt = 0; nt < 2; ++nt)
                bk[nt] = *(const bf16x8*)(Ks + (wave * 32 + nt * 16 + l16) * 72 + kd * 32 + qd * 8);
            #pragma unroll
            for (int mt = 0; mt < 2; ++mt)
                #pragma unroll
                for (int nt = 0; nt < 2; ++nt)
                    acc[mt][nt] = __builtin_amdgcn_mfma_f32_16x16x32_bf16(af[mt], bk[nt], acc[mt][nt], 0, 0, 0);
        }
        #pragma unroll
        for (int mt = 0; mt < 2; ++mt)
            #pragma unroll
            for (int nt = 0; nt < 2; ++nt) {
                const int key = kt + wave * 32 + nt * 16 + l16;
                const float bv = biasv[key];
                #pragma unroll
                for (int r = 0; r < 4; ++r) {
                    const int qr = mt * 16 + qd * 4 + r;
                    sc16[qr * 520 + key] = f2b(acc[mt][nt][r] * 0.125f + bv);
                }
            }
        __syncthreads();
    }

    // ---- softmax in place (wave per row, lane holds 8 contiguous keys) ----
    for (int i = 0; i < 8; ++i) {
        const int qr = wave * 8 + i;
        uint4 pv = *(const uint4*)(sc16 + qr * 520 + lane * 8);
        float f[8];
        up2(pv.x, f[0], f[1]); up2(pv.y, f[2], f[3]);
        up2(pv.z, f[4], f[5]); up2(pv.w, f[6], f[7]);
        float mx = f[0];
        #pragma unroll
        for (int j = 1; j < 8; ++j) mx = fmaxf(mx, f[j]);
        #pragma unroll
        for (int m = 32; m >= 1; m >>= 1) mx = fmaxf(mx, __shfl_xor(mx, m));
        float s = 0.f;
        #pragma unroll
        for (int j = 0; j < 8; ++j) { f[j] = __expf(f[j] - mx); s += f[j]; }
        #pragma unroll
        for (int m = 32; m >= 1; m >>= 1) s += __shfl_xor(s, m);
        const float inv = 1.0f / s;
        uint4 ov;
        ov.x = (u32)f2b(f[0] * inv) | ((u32)f2b(f[1] * inv) << 16);
        ov.y = (u32)f2b(f[2] * inv) | ((u32)f2b(f[3] * inv) << 16);
        ov.z = (u32)f2b(f[4] * inv) | ((u32)f2b(f[5] * inv) << 16);
        ov.w = (u32)f2b(f[6] * inv) | ((u32)f2b(f[7] * inv) << 16);
        *(uint4*)(sc16 + qr * 520 + lane * 8) = ov;
    }
    __syncthreads();

    // ---- PV (VALU fp32): thread = (d-pair, 4 q-rows) ----
    const int dp = tid & 31, qb = tid >> 5;
    float a[4][2];
    #pragma unroll
    for (int i = 0; i < 4; ++i) { a[i][0] = 0.f; a[i][1] = 0.f; }
    const u32* V32 = (const u32*)(Vb + base);       // row stride 384 u32
    for (int kc = 0; kc < 64; ++kc) {
        uint4 pr[4];
        #pragma unroll
        for (int i = 0; i < 4; ++i)
            pr[i] = *(const uint4*)(sc16 + (qb * 4 + i) * 520 + kc * 8);
        float p[4][8];
        #pragma unroll
        for (int i = 0; i < 4; ++i) {
            up2(pr[i].x, p[i][0], p[i][1]); up2(pr[i].y, p[i][2], p[i][3]);
            up2(pr[i].z, p[i][4], p[i][5]); up2(pr[i].w, p[i][6], p[i][7]);
        }
        #pragma unroll
        for (int j = 0; j < 8; ++j) {
            const int key = kc * 8 + j;
            float v0, v1; up2(V32[(size_t)key * 384 + dp], v0, v1);
            #pragma unroll
            for (int i = 0; i < 4; ++i) { a[i][0] += p[i][j] * v0; a[i][1] += p[i][j] * v1; }
        }
    }
    #pragma unroll
    for (int i = 0; i < 4; ++i) {
        const int qr = qb * 4 + i;
        u32 o = (u32)f2b(a[i][0]) | ((u32)f2b(a[i][1]) << 16);
        *(u32*)(Cb + base + (size_t)(qt * 32 + qr) * H_ + dp * 2) = o;
    }
}

// ---------- head: pooled -> tanh(pooled@Wp1+bp1) ----------
__global__ __launch_bounds__(256) void head1_kernel(
    const float* __restrict__ x32, const void* __restrict__ Wp1,
    const void* __restrict__ bp1, float* __restrict__ hid, const int* __restrict__ fl) {
    __shared__ float pl[H_];
    const int bf = fl[0];
    const int b = blockIdx.x, t = threadIdx.x;
    const float* xr = x32 + (size_t)b * S_ * H_;      // row (b, s=0)
    for (int c = t; c < H_; c += 256) pl[c] = xr[c];
    __syncthreads();
    for (int j = t; j < H_; j += 256) {
        float acc = lda(bp1, j, bf);
        for (int k = 0; k < H_; ++k) acc += pl[k] * lda(Wp1, (size_t)k * H_ + j, bf);
        hid[(size_t)b * H_ + j] = tanhf(acc);
    }
}

// ---------- head: logits + log-softmax loss, dual-format output ----------
__global__ __launch_bounds__(256) void head2_kernel(
    const float* __restrict__ hid, const void* __restrict__ Wp2,
    const void* __restrict__ bp2, const int* __restrict__ tgt,
    void* __restrict__ outv, const int* __restrict__ fl) {
    __shared__ float lg[B_ * LAB_];
    __shared__ float lse[B_];
    const int bf = fl[0];
    const int t = threadIdx.x;
    if (t < B_ * LAB_) {
        const int b = t / LAB_, j = t % LAB_;
        float acc = lda(bp2, j, bf);
        for (int k = 0; k < H_; ++k) acc += hid[(size_t)b * H_ + k] * lda(Wp2, (size_t)k * LAB_ + j, bf);
        lg[t] = acc;
    }
    __syncthreads();
    if (t < B_) {
        float mx = -1e30f;
        for (int j = 0; j < LAB_; ++j) mx = fmaxf(mx, lg[t * LAB_ + j]);
        float s = 0.f;
        for (int j = 0; j < LAB_; ++j) s += expf(lg[t * LAB_ + j] - mx);
        lse[t] = mx + logf(s);
    }
    __syncthreads();
    float loss = 0.f;
    if (t == 0) {
        for (int b = 0; b < B_; ++b) loss += lse[b] - lg[b * LAB_ + tgt[b]];
        loss /= (float)B_;
    }
    if (bf) {
        u16* o = (u16*)outv;
        if (t == 0) o[0] = f2b(loss);
        if (t < B_ * LAB_) o[1 + t] = f2b(lg[t]);
    } else {
        float* o = (float*)outv;
        if (t == 0) o[0] = loss;
        if (t < B_ * LAB_) o[1 + t] = lg[t];
    }
}

// ---------- launch ----------
extern "C" void kernel_launch(void* const* d_in, const int* in_sizes, int n_in,
                              void* d_out, int out_size, void* d_ws, size_t ws_size,
                              hipStream_t stream) {
    (void)in_sizes; (void)n_in; (void)out_size; (void)ws_size;
    const int* src = (const int*)d_in[0];
    const int* seg = (const int*)d_in[1];
    const int* tgt = (const int*)d_in[2];
    const int* tib = (const int*)d_in[3];
    const void* we  = d_in[4];
    const void* pe  = d_in[5];
    const void* se  = d_in[6];
    const void* elg = d_in[7];
    const void* elb = d_in[8];
    const void* Wq  = d_in[9];
    const void* bq  = d_in[10];
    const void* Wk  = d_in[11];
    const void* bk  = d_in[12];
    const void* Wv  = d_in[13];
    const void* bv  = d_in[14];
    const void* Wo  = d_in[15];
    const void* bo  = d_in[16];
    const void* l1g = d_in[17];
    const void* l1b = d_in[18];
    const void* Wf1 = d_in[19];
    const void* bf1 = d_in[20];
    const void* Wf2 = d_in[21];
    const void* bf2 = d_in[22];
    const void* l2g = d_in[23];
    const void* l2b = d_in[24];
    const void* Wp1 = d_in[25];
    const void* bp1 = d_in[26];
    const void* Wp2 = d_in[27];
    const void* bp2 = d_in[28];
    const void* sf  = d_in[29];

    const size_t HH  = (size_t)H_ * H_;       // 589824
    const size_t HFF = (size_t)H_ * FF_;      // 2359296
    const size_t MH  = (size_t)M_ * H_;       // 6291456
    const size_t MFF = (size_t)M_ * FF_;      // 25165824

    char* w = (char*)d_ws;
    int* dflag = (int*)w;  w += 256;
    u16* WqT  = (u16*)w;  w += L_ * HH  * 2;
    u16* WkT  = (u16*)w;  w += L_ * HH  * 2;
    u16* WvT  = (u16*)w;  w += L_ * HH  * 2;
    u16* WoT  = (u16*)w;  w += L_ * HH  * 2;
    u16* Wf1T = (u16*)w;  w += L_ * HFF * 2;
    u16* Wf2T = (u16*)w;  w += L_ * HFF * 2;
    float* x32 = (float*)w; w += MH * 4;
    u16* xb   = (u16*)w;  w += MH * 2;
    u16* qb_  = (u16*)w;  w += MH * 2;
    u16* kb_  = (u16*)w;  w += MH * 2;
    u16* vb_  = (u16*)w;  w += MH * 2;
    u16* ctxb = (u16*)w;  w += MH * 2;
    u16* tmpb = (u16*)w;  w += MH * 2;
    u16* ffb  = (u16*)w;  w += MFF * 2;
    float* hid = (float*)w; w += (size_t)B_ * H_ * 4;

    const dim3 tb(256);
    detect_kernel<<<1, 1, 0, stream>>>((const u32*)elg, dflag);

    // weight transposes+convert (K x N -> N x K bf16), z = layer
    transpose_k<<<dim3(12, 12, 6), tb, 0, stream>>>(Wq,  WqT,  H_, H_, dflag);
    transpose_k<<<dim3(12, 12, 6), tb, 0, stream>>>(Wk,  WkT,  H_, H_, dflag);
    transpose_k<<<dim3(12, 12, 6), tb, 0, stream>>>(Wv,  WvT,  H_, H_, dflag);
    transpose_k<<<dim3(12, 12, 6), tb, 0, stream>>>(Wo,  WoT,  H_, H_, dflag);
    transpose_k<<<dim3(48, 12, 6), tb, 0, stream>>>(Wf1, Wf1T, H_, FF_, dflag);
    transpose_k<<<dim3(12, 48, 6), tb, 0, stream>>>(Wf2, Wf2T, FF_, H_, dflag);

    embed_kernel<<<M_, tb, 0, stream>>>(src, seg, tib, we, pe, se, elg, elb, sf, x32, xb, dflag);

    for (int l = 0; l < L_; ++l) {
        gemm_bt<<<dim3(H_ / 128, M_ / 128), tb, 0, stream>>>(xb, WqT + l * HH, bq, (long)l * H_, qb_, M_, H_, H_, 0, dflag);
        gemm_bt<<<dim3(H_ / 128, M_ / 128), tb, 0, stream>>>(xb, WkT + l * HH, bk, (long)l * H_, kb_, M_, H_, H_, 0, dflag);
        gemm_bt<<<dim3(H_ / 128, M_ / 128), tb, 0, stream>>>(xb, WvT + l * HH, bv, (long)l * H_, vb_, M_, H_, H_, 0, dflag);
        attn_kernel<<<dim3(S_ / 32, NH_, B_), tb, 0, stream>>>(qb_, kb_, vb_, seg, ctxb);
        gemm_bt<<<dim3(H_ / 128, M_ / 128), tb, 0, stream>>>(ctxb, WoT + l * HH, bo, (long)l * H_, tmpb, M_, H_, H_, 0, dflag);
        add_ln_kernel<<<M_, tb, 0, stream>>>(x32, tmpb, l1g, l1b, (long)l * H_, x32, xb, dflag);
        gemm_bt<<<dim3(FF_ / 128, M_ / 128), tb, 0, stream>>>(xb, Wf1T + l * HFF, bf1, (long)l * FF_, ffb, M_, FF_, H_, 1, dflag);
        gemm_bt<<<dim3(H_ / 128, M_ / 128), tb, 0, stream>>>(ffb, Wf2T + l * HFF, bf2, (long)l * H_, tmpb, M_, H_, FF_, 0, dflag);
        add_ln_kernel<<<M_, tb, 0, stream>>>(x32, tmpb, l2g, l2b, (long)l * H_, x32, xb, dflag);
    }

    head1_kernel<<<B_, tb, 0, stream>>>(x32, Wp1, bp1, hid, dflag);
    head2_kernel<<<1, tb, 0, stream>>>(hid, Wp2, bp2, tgt, d_out, dflag);
}

// Round 4
// 2595.572 us; speedup vs baseline: 1.5465x; 1.5465x over previous
//
#include <hip/hip_runtime.h>

typedef unsigned short u16;
typedef unsigned int   u32;
typedef __bf16  bf16x8 __attribute__((ext_vector_type(8)));
typedef float   f32x4  __attribute__((ext_vector_type(4)));

#define B_   16
#define S_   512
#define H_   768
#define NH_  12
#define L_   6
#define FF_  3072
#define M_   8192     // B_*S_
#define LAB_ 10
#define STRQ 2304     // merged qkv row stride

// ---------- bf16 helpers (storage = u16 bits) ----------
__device__ __forceinline__ float b2f(u16 x) {
    u32 u = ((u32)x) << 16; float f; __builtin_memcpy(&f, &u, 4); return f;
}
__device__ __forceinline__ u16 f2b(float f) {
    u32 u; __builtin_memcpy(&u, &f, 4);
    u32 r = u + 0x7FFFu + ((u >> 16) & 1u);
    return (u16)(r >> 16);
}
__device__ __forceinline__ void up2(u32 u, float& a, float& b) {
    u32 lo = u << 16, hi = u & 0xFFFF0000u;
    __builtin_memcpy(&a, &lo, 4); __builtin_memcpy(&b, &hi, 4);
}
// dtype-dispatched load of a float input: bf=1 -> bf16 storage, bf=0 -> fp32 storage
__device__ __forceinline__ float lda(const void* p, size_t i, int bf) {
    return bf ? b2f(((const u16*)p)[i]) : ((const float*)p)[i];
}
__device__ __forceinline__ float gelu_tanh(float x) {
    return 0.5f * x * (1.0f + tanhf(0.7978845608028654f * (x + 0.044715f * x * x * x)));
}
// async global->LDS, 16B per lane; LDS dest must be wave-uniform base + lane*16
__device__ __forceinline__ void async_lds16(const u16* g, u16* l) {
    __builtin_amdgcn_global_load_lds(
        (const __attribute__((address_space(1))) u32*)(const void*)g,
        (__attribute__((address_space(3))) u32*)(void*)l, 16, 0, 0);
}

// ---------- dtype detect: emb_ln_g is all ones ----------
__global__ void detect_kernel(const u32* __restrict__ g, int* __restrict__ flag) {
    flag[0] = (g[0] == 0x3F803F80u) ? 1 : 0;   // bf16 ones pair vs fp32 one
}

// ---------- block reduce (sum of two values), 256 threads ----------
__device__ __forceinline__ void block_reduce2(float& s, float& s2, float* red, int tid) {
    int lane = tid & 63, wave = tid >> 6;
    #pragma unroll
    for (int m = 32; m >= 1; m >>= 1) { s += __shfl_xor(s, m); s2 += __shfl_xor(s2, m); }
    if (lane == 0) { red[wave] = s; red[4 + wave] = s2; }
    __syncthreads();
    s  = red[0] + red[1] + red[2] + red[3];
    s2 = red[4] + red[5] + red[6] + red[7];
}

// ---------- weight transpose+convert: in (K x N) -> out bf16 (N x K) ----------
__global__ __launch_bounds__(256) void transpose_k(const void* __restrict__ in,
                                                   u16* __restrict__ out, int K, int N,
                                                   long in_lstride, long out_lstride,
                                                   const int* __restrict__ fl) {
    __shared__ u16 tile[64][65];
    const int bf = fl[0];
    const size_t ioff = (size_t)blockIdx.z * (size_t)in_lstride;
    const size_t ooff = (size_t)blockIdx.z * (size_t)out_lstride;
    int k0 = blockIdx.y * 64, n0 = blockIdx.x * 64;
    int c = threadIdx.x & 63, r0 = threadIdx.x >> 6;
    #pragma unroll
    for (int r = r0; r < 64; r += 4) {
        size_t idx = ioff + (size_t)(k0 + r) * N + n0 + c;
        tile[r][c] = bf ? ((const u16*)in)[idx] : f2b(((const float*)in)[idx]);
    }
    __syncthreads();
    #pragma unroll
    for (int r = r0; r < 64; r += 4)
        out[ooff + (size_t)(n0 + r) * K + k0 + c] = tile[c][r];
}

// ---------- bias prep: convert all GEMM biases to bf16, qkv concatenated ----------
// layout: [0,13824) bqkv (6 x 2304) | [13824,18432) bo | [18432,36864) bf1 | [36864,41472) bf2
__global__ __launch_bounds__(256) void prep_bias(
    const void* __restrict__ bq, const void* __restrict__ bk, const void* __restrict__ bv,
    const void* __restrict__ bo, const void* __restrict__ bf1, const void* __restrict__ bf2,
    u16* __restrict__ out, const int* __restrict__ fl) {
    const int bf = fl[0];
    int i = blockIdx.x * 256 + threadIdx.x;
    if (i >= 41472) return;
    float v;
    if (i < 13824) {
        int l = i / 2304, c = i % 2304;
        v = (c < 768) ? lda(bq, (size_t)l * 768 + c, bf)
          : (c < 1536) ? lda(bk, (size_t)l * 768 + c - 768, bf)
                       : lda(bv, (size_t)l * 768 + c - 1536, bf);
    } else if (i < 18432) v = lda(bo,  i - 13824, bf);
    else if (i < 36864)   v = lda(bf1, i - 18432, bf);
    else                  v = lda(bf2, i - 36864, bf);
    out[i] = f2b(v);
}

// ---------- embedding + LN + selection scale ----------
__global__ __launch_bounds__(256) void embed_kernel(
    const int* __restrict__ src, const int* __restrict__ seg, const int* __restrict__ tib,
    const void* __restrict__ we, const void* __restrict__ pe, const void* __restrict__ se,
    const void* __restrict__ g, const void* __restrict__ bb, const void* __restrict__ sf,
    float* __restrict__ x32, u16* __restrict__ xb, const int* __restrict__ fl) {
    __shared__ float red[8];
    const int bf = fl[0];
    const int r = blockIdx.x, tid = threadIdx.x;
    const int s = r & (S_ - 1);
    const int w = src[r], sg = seg[r];
    const float scale = lda(sf, tib[r], bf);
    float v[3]; int col[3];
    #pragma unroll
    for (int i = 0; i < 3; ++i) {
        col[i] = tid + i * 256;
        v[i] = lda(we, (size_t)w * H_ + col[i], bf) + lda(pe, (size_t)s * H_ + col[i], bf)
             + lda(se, (size_t)sg * H_ + col[i], bf);
    }
    float su = v[0] + v[1] + v[2];
    float sq = v[0]*v[0] + v[1]*v[1] + v[2]*v[2];
    block_reduce2(su, sq, red, tid);
    const float mean = su * (1.0f / H_);
    const float var  = sq * (1.0f / H_) - mean * mean;
    const float inv  = rsqrtf(var + 1e-5f);
    #pragma unroll
    for (int i = 0; i < 3; ++i) {
        float y = ((v[i] - mean) * inv * lda(g, col[i], bf) + lda(bb, col[i], bf)) * scale;
        x32[(size_t)r * H_ + col[i]] = y;
        xb [(size_t)r * H_ + col[i]] = f2b(y);
    }
}

// ---------- residual add + LN (x32 master, bf16 shadow out) ----------
__global__ __launch_bounds__(256) void add_ln_kernel(
    const float* __restrict__ xin, const u16* __restrict__ t,
    const void* __restrict__ g, const void* __restrict__ bb, long goff,
    float* __restrict__ xout, u16* __restrict__ xb, const int* __restrict__ fl) {
    __shared__ float red[8];
    const int bf = fl[0];
    const int r = blockIdx.x, tid = threadIdx.x;
    const size_t rb = (size_t)r * H_;
    float v[3]; int col[3];
    #pragma unroll
    for (int i = 0; i < 3; ++i) {
        col[i] = tid + i * 256;
        v[i] = xin[rb + col[i]] + b2f(t[rb + col[i]]);
    }
    float su = v[0] + v[1] + v[2];
    float sq = v[0]*v[0] + v[1]*v[1] + v[2]*v[2];
    block_reduce2(su, sq, red, tid);
    const float mean = su * (1.0f / H_);
    const float var  = sq * (1.0f / H_) - mean * mean;
    const float inv  = rsqrtf(var + 1e-5f);
    #pragma unroll
    for (int i = 0; i < 3; ++i) {
        float y = (v[i] - mean) * inv * lda(g, goff + col[i], bf) + lda(bb, goff + col[i], bf);
        xout[rb + col[i]] = y;
        xb  [rb + col[i]] = f2b(y);
    }
}

// ---------- MFMA GEMM (m97-style async staging): C[M,N] = A * Bt^T + bias ----------
__global__ __launch_bounds__(256) void gemm_bt(
    const u16* __restrict__ A, const u16* __restrict__ Bt, const u16* __restrict__ bias,
    u16* __restrict__ C, int M, int N, int K, int act) {
    __shared__ alignas(16) u16 As[128 * 32];
    __shared__ alignas(16) u16 Bs[128 * 32];
    const int tid = threadIdx.x;
    const int bm = blockIdx.y * 128, bn = blockIdx.x * 128;
    const int wave = tid >> 6, lane = tid & 63;
    const int wm = (wave >> 1) * 64, wn = (wave & 1) * 64;
    const int qd = lane >> 4, l16 = lane & 15;

    const f32x4 fz = {0.f, 0.f, 0.f, 0.f};
    f32x4 acc[4][4];
    #pragma unroll
    for (int i = 0; i < 4; ++i)
        #pragma unroll
        for (int j = 0; j < 4; ++j) acc[i][j] = fz;

    const int c0 = tid, c1 = tid + 256;
    const int r0 = c0 >> 2, cc0 = (c0 & 3) * 8;
    const int r1 = c1 >> 2, cc1 = (c1 & 3) * 8;
    const u16* A0 = A  + (size_t)(bm + r0) * K + cc0;
    const u16* A1 = A  + (size_t)(bm + r1) * K + cc1;
    const u16* B0 = Bt + (size_t)(bn + r0) * K + cc0;
    const u16* B1 = Bt + (size_t)(bn + r1) * K + cc1;

    for (int k0 = 0; k0 < K; k0 += 32) {
        __syncthreads();               // prev iter's LDS reads complete
        async_lds16(A0 + k0, As + c0 * 8);
        async_lds16(A1 + k0, As + c1 * 8);
        async_lds16(B0 + k0, Bs + c0 * 8);
        async_lds16(B1 + k0, Bs + c1 * 8);
        __syncthreads();               // vmcnt drained by barrier semantics
        bf16x8 af[4], bfv[4];
        #pragma unroll
        for (int i = 0; i < 4; ++i)
            af[i] = *(const bf16x8*)(As + (wm + i * 16 + l16) * 32 + qd * 8);
        #pragma unroll
        for (int j = 0; j < 4; ++j)
            bfv[j] = *(const bf16x8*)(Bs + (wn + j * 16 + l16) * 32 + qd * 8);
        #pragma unroll
        for (int i = 0; i < 4; ++i)
            #pragma unroll
            for (int j = 0; j < 4; ++j)
                acc[i][j] = __builtin_amdgcn_mfma_f32_16x16x32_bf16(af[i], bfv[j], acc[i][j], 0, 0, 0);
    }

    // epilogue: C/D layout col=lane&15, row=(lane>>4)*4+reg
    #pragma unroll
    for (int i = 0; i < 4; ++i) {
        const int row0 = bm + wm + i * 16 + qd * 4;
        #pragma unroll
        for (int j = 0; j < 4; ++j) {
            const int col = bn + wn + j * 16 + l16;
            const float bv = b2f(bias[col]);
            #pragma unroll
            for (int r = 0; r < 4; ++r) {
                float v = acc[i][j][r] + bv;
                if (act == 1) v = gelu_tanh(v);
                C[(size_t)(row0 + r) * N + col] = f2b(v);
            }
        }
    }
}

// ---------- flash attention: 64 queries/block, online softmax, MFMA QK^T and PV ----------
__global__ __launch_bounds__(256) void attn_kernel(
    const u16* __restrict__ QKV, const int* __restrict__ seg, u16* __restrict__ Cb) {
    __shared__ alignas(16) u16 Qs[64 * 72];     // [q][d]
    __shared__ alignas(16) u16 Ks[128 * 72];    // [key][d]
    __shared__ alignas(16) u16 Vt[64 * 136];    // [d][key] with 16B-block xor swizzle
    __shared__ alignas(16) u16 Ps[64 * 136];    // [q][key]
    __shared__ float biasv[512];
    const int tid = threadIdx.x;
    const int qt = blockIdx.x, h = blockIdx.y, b = blockIdx.z;
    const int wave = tid >> 6, lane = tid & 63;
    const int qd = lane >> 4, l16 = lane & 15;
    const u16* Qg = QKV + (size_t)b * S_ * STRQ + h * 64;
    const u16* Kg = Qg + 768;
    const u16* Vg = Qg + 1536;

    for (int i = tid; i < 512; i += 256)
        biasv[i] = (seg[b * S_ + i] > 0) ? 0.0f : -1e9f;

    {   // stage Q tile 64x64 = 512 uint4 items
        int c = tid;
        #pragma unroll
        for (int u = 0; u < 2; ++u, c += 256) {
            int r = c >> 3, c8 = (c & 7) * 8;
            uint4 v4 = *(const uint4*)(Qg + (size_t)(qt * 64 + r) * STRQ + c8);
            *(uint4*)(Qs + r * 72 + c8) = v4;
        }
    }

    float m_run[4], l_run[4];
    f32x4 accO[4];
    #pragma unroll
    for (int r = 0; r < 4; ++r) { m_run[r] = -3.0e38f; l_run[r] = 0.f; }
    #pragma unroll
    for (int dt = 0; dt < 4; ++dt) accO[dt] = {0.f, 0.f, 0.f, 0.f};

    for (int kt = 0; kt < 512; kt += 128) {
        __syncthreads();                       // prev iter's Ks/Vt reads complete
        {   // stage K tile 128x64 = 1024 uint4 items
            int c = tid;
            #pragma unroll
            for (int u = 0; u < 4; ++u, c += 256) {
                int r = c >> 3, c8 = (c & 7) * 8;
                uint4 v4 = *(const uint4*)(Kg + (size_t)(kt + r) * STRQ + c8);
                *(uint4*)(Ks + r * 72 + c8) = v4;
            }
        }
        {   // stage V tile transposed: Vt[d][key], key-block xor-swizzled (1024 items)
            int c = tid;
            #pragma unroll
            for (int u = 0; u < 4; ++u, c += 256) {
                int r = c >> 3, d8 = (c & 7) * 8;
                uint4 v4 = *(const uint4*)(Vg + (size_t)(kt + r) * STRQ + d8);
                u16 tmp[8]; *(uint4*)tmp = v4;
                #pragma unroll
                for (int j = 0; j < 8; ++j) {
                    int d = d8 + j;
                    int blk = (r >> 3) ^ (d >> 3);
                    Vt[d * 136 + blk * 8 + (r & 7)] = tmp[j];
                }
            }
        }
        __syncthreads();

        // ---- QK^T: wave owns q rows wave*16..+15, all 128 keys ----
        f32x4 s[8];
        {
            bf16x8 aq[2];
            #pragma unroll
            for (int kd = 0; kd < 2; ++kd)
                aq[kd] = *(const bf16x8*)(Qs + (wave * 16 + l16) * 72 + kd * 32 + qd * 8);
            #pragma unroll
            for (int nt = 0; nt < 8; ++nt) {
                s[nt] = {0.f, 0.f, 0.f, 0.f};
                #pragma unroll
                for (int kd = 0; kd < 2; ++kd) {
                    bf16x8 bk = *(const bf16x8*)(Ks + (nt * 16 + l16) * 72 + kd * 32 + qd * 8);
                    s[nt] = __builtin_amdgcn_mfma_f32_16x16x32_bf16(aq[kd], bk, s[nt], 0, 0, 0);
                }
            }
        }
        // scale + mask bias (bias depends on key = col = nt*16+l16)
        #pragma unroll
        for (int nt = 0; nt < 8; ++nt) {
            const float bv = biasv[kt + nt * 16 + l16];
            #pragma unroll
            for (int r = 0; r < 4; ++r) s[nt][r] = s[nt][r] * 0.125f + bv;
        }
        // online softmax: rows live in (qd, r); reduce across 16 l16 lanes
        float alpha[4], rsum[4];
        #pragma unroll
        for (int r = 0; r < 4; ++r) {
            float m = s[0][r];
            #pragma unroll
            for (int nt = 1; nt < 8; ++nt) m = fmaxf(m, s[nt][r]);
            #pragma unroll
            for (int msk = 8; msk >= 1; msk >>= 1) m = fmaxf(m, __shfl_xor(m, msk));
            float mn = fmaxf(m_run[r], m);
            alpha[r] = __expf(m_run[r] - mn);
            m_run[r] = mn;
            rsum[r] = 0.f;
        }
        #pragma unroll
        for (int nt = 0; nt < 8; ++nt)
            #pragma unroll
            for (int r = 0; r < 4; ++r) {
                float p = __expf(s[nt][r] - m_run[r]);
                rsum[r] += p;
                Ps[(wave * 16 + qd * 4 + r) * 136 + nt * 16 + l16] = f2b(p);
            }
        #pragma unroll
        for (int r = 0; r < 4; ++r) {
            float t = rsum[r];
            #pragma unroll
            for (int msk = 8; msk >= 1; msk >>= 1) t += __shfl_xor(t, msk);
            l_run[r] = l_run[r] * alpha[r] + t;
        }
        #pragma unroll
        for (int dt = 0; dt < 4; ++dt)
            #pragma unroll
            for (int r = 0; r < 4; ++r) accO[dt][r] *= alpha[r];
        __syncthreads();                       // Ps visible (and Vt already staged)

        // ---- PV: O(16x64) += P(16x128) @ V(128x64) ----
        #pragma unroll
        for (int kk = 0; kk < 4; ++kk) {
            bf16x8 ap = *(const bf16x8*)(Ps + (wave * 16 + l16) * 136 + kk * 32 + qd * 8);
            #pragma unroll
            for (int dt = 0; dt < 4; ++dt) {
                const int d = dt * 16 + l16;
                const int blk = (kk * 4 + qd) ^ (d >> 3);
                bf16x8 bv = *(const bf16x8*)(Vt + d * 136 + blk * 8);
                accO[dt] = __builtin_amdgcn_mfma_f32_16x16x32_bf16(ap, bv, accO[dt], 0, 0, 0);
            }
        }
    }

    // epilogue: normalize and write ctx [row][h*64+d]
    #pragma unroll
    for (int r = 0; r < 4; ++r) {
        const int row = qt * 64 + wave * 16 + qd * 4 + r;
        const float inv = 1.0f / l_run[r];
        const size_t obase = ((size_t)b * S_ + row) * H_ + h * 64;
        #pragma unroll
        for (int dt = 0; dt < 4; ++dt)
            Cb[obase + dt * 16 + l16] = f2b(accO[dt][r] * inv);
    }
}

// ---------- head: pooled -> tanh(pooled@Wp1+bp1) ----------
__global__ __launch_bounds__(256) void head1_kernel(
    const float* __restrict__ x32, const void* __restrict__ Wp1,
    const void* __restrict__ bp1, float* __restrict__ hid, const int* __restrict__ fl) {
    __shared__ float pl[H_];
    const int bf = fl[0];
    const int b = blockIdx.x, t = threadIdx.x;
    const float* xr = x32 + (size_t)b * S_ * H_;      // row (b, s=0)
    for (int c = t; c < H_; c += 256) pl[c] = xr[c];
    __syncthreads();
    for (int j = t; j < H_; j += 256) {
        float acc = lda(bp1, j, bf);
        for (int k = 0; k < H_; ++k) acc += pl[k] * lda(Wp1, (size_t)k * H_ + j, bf);
        hid[(size_t)b * H_ + j] = tanhf(acc);
    }
}

// ---------- head: logits + log-softmax loss, dual-format output ----------
__global__ __launch_bounds__(256) void head2_kernel(
    const float* __restrict__ hid, const void* __restrict__ Wp2,
    const void* __restrict__ bp2, const int* __restrict__ tgt,
    void* __restrict__ outv, const int* __restrict__ fl) {
    __shared__ float lg[B_ * LAB_];
    __shared__ float lse[B_];
    const int bf = fl[0];
    const int t = threadIdx.x;
    if (t < B_ * LAB_) {
        const int b = t / LAB_, j = t % LAB_;
        float acc = lda(bp2, j, bf);
        for (int k = 0; k < H_; ++k) acc += hid[(size_t)b * H_ + k] * lda(Wp2, (size_t)k * LAB_ + j, bf);
        lg[t] = acc;
    }
    __syncthreads();
    if (t < B_) {
        float mx = -1e30f;
        for (int j = 0; j < LAB_; ++j) mx = fmaxf(mx, lg[t * LAB_ + j]);
        float s = 0.f;
        for (int j = 0; j < LAB_; ++j) s += expf(lg[t * LAB_ + j] - mx);
        lse[t] = mx + logf(s);
    }
    __syncthreads();
    float loss = 0.f;
    if (t == 0) {
        for (int b = 0; b < B_; ++b) loss += lse[b] - lg[b * LAB_ + tgt[b]];
        loss /= (float)B_;
    }
    if (bf) {
        u16* o = (u16*)outv;
        if (t == 0) o[0] = f2b(loss);
        if (t < B_ * LAB_) o[1 + t] = f2b(lg[t]);
    } else {
        float* o = (float*)outv;
        if (t == 0) o[0] = loss;
        if (t < B_ * LAB_) o[1 + t] = lg[t];
    }
}

// ---------- launch ----------
extern "C" void kernel_launch(void* const* d_in, const int* in_sizes, int n_in,
                              void* d_out, int out_size, void* d_ws, size_t ws_size,
                              hipStream_t stream) {
    (void)in_sizes; (void)n_in; (void)out_size; (void)ws_size;
    const int* src = (const int*)d_in[0];
    const int* seg = (const int*)d_in[1];
    const int* tgt = (const int*)d_in[2];
    const int* tib = (const int*)d_in[3];
    const void* we  = d_in[4];
    const void* pe  = d_in[5];
    const void* se  = d_in[6];
    const void* elg = d_in[7];
    const void* elb = d_in[8];
    const void* Wq  = d_in[9];
    const void* bq  = d_in[10];
    const void* Wk  = d_in[11];
    const void* bk  = d_in[12];
    const void* Wv  = d_in[13];
    const void* bv  = d_in[14];
    const void* Wo  = d_in[15];
    const void* bo  = d_in[16];
    const void* l1g = d_in[17];
    const void* l1b = d_in[18];
    const void* Wf1 = d_in[19];
    const void* bf1 = d_in[20];
    const void* Wf2 = d_in[21];
    const void* bf2 = d_in[22];
    const void* l2g = d_in[23];
    const void* l2b = d_in[24];
    const void* Wp1 = d_in[25];
    const void* bp1 = d_in[26];
    const void* Wp2 = d_in[27];
    const void* bp2 = d_in[28];
    const void* sf  = d_in[29];

    const size_t HH   = (size_t)H_ * H_;        // 589824
    const size_t HFF  = (size_t)H_ * FF_;       // 2359296
    const size_t MH   = (size_t)M_ * H_;        // 6291456
    const size_t MQKV = (size_t)M_ * STRQ;      // 18874368
    const size_t MFF  = (size_t)M_ * FF_;       // 25165824
    const size_t QKVW = (size_t)STRQ * H_;      // 1769472 (per-layer merged weight)

    char* w = (char*)d_ws;
    int* dflag  = (int*)w;  w += 256;
    u16* bias_ws = (u16*)w; w += 41472 * 2;     // prep_bias layout
    u16* WqkvT = (u16*)w;  w += L_ * QKVW * 2;
    u16* WoT   = (u16*)w;  w += L_ * HH  * 2;
    u16* Wf1T  = (u16*)w;  w += L_ * HFF * 2;
    u16* Wf2T  = (u16*)w;  w += L_ * HFF * 2;
    float* x32 = (float*)w; w += MH * 4;
    u16* xb    = (u16*)w;  w += MH * 2;
    u16* qkvb  = (u16*)w;  w += MQKV * 2;
    u16* ctxb  = (u16*)w;  w += MH * 2;
    u16* tmpb  = (u16*)w;  w += MH * 2;
    u16* ffb   = (u16*)w;  w += MFF * 2;
    float* hid = (float*)w; w += (size_t)B_ * H_ * 4;

    u16* bqkv = bias_ws;            // 6 x 2304
    u16* bo6  = bias_ws + 13824;    // 6 x 768
    u16* bf16_= bias_ws + 18432;    // 6 x 3072
    u16* bf26 = bias_ws + 36864;    // 6 x 768

    const dim3 tb(256);
    detect_kernel<<<1, 1, 0, stream>>>((const u32*)elg, dflag);
    prep_bias<<<162, tb, 0, stream>>>(bq, bk, bv, bo, bf1, bf2, bias_ws, dflag);

    // weight transposes+convert; Wq/Wk/Wv interleave into per-layer 2304x768 blocks
    transpose_k<<<dim3(12, 12, 6), tb, 0, stream>>>(Wq, WqkvT,                    H_, H_, (long)HH, (long)QKVW, dflag);
    transpose_k<<<dim3(12, 12, 6), tb, 0, stream>>>(Wk, WqkvT + (size_t)768*768,  H_, H_, (long)HH, (long)QKVW, dflag);
    transpose_k<<<dim3(12, 12, 6), tb, 0, stream>>>(Wv, WqkvT + (size_t)1536*768, H_, H_, (long)HH, (long)QKVW, dflag);
    transpose_k<<<dim3(12, 12, 6), tb, 0, stream>>>(Wo,  WoT,  H_, H_,  (long)HH,  (long)HH,  dflag);
    transpose_k<<<dim3(48, 12, 6), tb, 0, stream>>>(Wf1, Wf1T, H_, FF_, (long)HFF, (long)HFF, dflag);
    transpose_k<<<dim3(12, 48, 6), tb, 0, stream>>>(Wf2, Wf2T, FF_, H_, (long)HFF, (long)HFF, dflag);

    embed_kernel<<<M_, tb, 0, stream>>>(src, seg, tib, we, pe, se, elg, elb, sf, x32, xb, dflag);

    for (int l = 0; l < L_; ++l) {
        gemm_bt<<<dim3(STRQ / 128, M_ / 128), tb, 0, stream>>>(xb, WqkvT + l * QKVW, bqkv + l * STRQ, qkvb, M_, STRQ, H_, 0);
        attn_kernel<<<dim3(S_ / 64, NH_, B_), tb, 0, stream>>>(qkvb, seg, ctxb);
        gemm_bt<<<dim3(H_ / 128, M_ / 128), tb, 0, stream>>>(ctxb, WoT + l * HH, bo6 + l * H_, tmpb, M_, H_, H_, 0);
        add_ln_kernel<<<M_, tb, 0, stream>>>(x32, tmpb, l1g, l1b, (long)l * H_, x32, xb, dflag);
        gemm_bt<<<dim3(FF_ / 128, M_ / 128), tb, 0, stream>>>(xb, Wf1T + l * HFF, bf16_ + l * FF_, ffb, M_, FF_, H_, 1);
        gemm_bt<<<dim3(H_ / 128, M_ / 128), tb, 0, stream>>>(ffb, Wf2T + l * HFF, bf26 + l * H_, tmpb, M_, H_, FF_, 0);
        add_ln_kernel<<<M_, tb, 0, stream>>>(x32, tmpb, l2g, l2b, (long)l * H_, x32, xb, dflag);
    }

    head1_kernel<<<B_, tb, 0, stream>>>(x32, Wp1, bp1, hid, dflag);
    head2_kernel<<<1, tb, 0, stream>>>(hid, Wp2, bp2, tgt, d_out, dflag);
}

// Round 5
// 2303.379 us; speedup vs baseline: 1.7427x; 1.1269x over previous
//
#include <hip/hip_runtime.h>

typedef unsigned short u16;
typedef unsigned int   u32;
typedef __bf16  bf16x8 __attribute__((ext_vector_type(8)));
typedef float   f32x4  __attribute__((ext_vector_type(4)));

#define B_   16
#define S_   512
#define H_   768
#define NH_  12
#define L_   6
#define FF_  3072
#define M_   8192     // B_*S_
#define LAB_ 10
#define STRQ 2304     // merged qkv row stride

// ---------- bf16 helpers (storage = u16 bits) ----------
__device__ __forceinline__ float b2f(u16 x) {
    u32 u = ((u32)x) << 16; float f; __builtin_memcpy(&f, &u, 4); return f;
}
__device__ __forceinline__ u16 f2b(float f) {
    u32 u; __builtin_memcpy(&u, &f, 4);
    u32 r = u + 0x7FFFu + ((u >> 16) & 1u);
    return (u16)(r >> 16);
}
__device__ __forceinline__ void up2(u32 u, float& a, float& b) {
    u32 lo = u << 16, hi = u & 0xFFFF0000u;
    __builtin_memcpy(&a, &lo, 4); __builtin_memcpy(&b, &hi, 4);
}
// dtype-dispatched load of a float input: bf=1 -> bf16 storage, bf=0 -> fp32 storage
__device__ __forceinline__ float lda(const void* p, size_t i, int bf) {
    return bf ? b2f(((const u16*)p)[i]) : ((const float*)p)[i];
}
__device__ __forceinline__ float gelu_tanh(float x) {
    return 0.5f * x * (1.0f + tanhf(0.7978845608028654f * (x + 0.044715f * x * x * x)));
}
// async global->LDS, 16B per lane; LDS dest must be wave-uniform base + lane*16
__device__ __forceinline__ void async_lds16(const u16* g, u16* l) {
    __builtin_amdgcn_global_load_lds(
        (const __attribute__((address_space(1))) u32*)(const void*)g,
        (__attribute__((address_space(3))) u32*)(void*)l, 16, 0, 0);
}

// ---------- dtype detect: emb_ln_g is all ones ----------
__global__ void detect_kernel(const u32* __restrict__ g, int* __restrict__ flag) {
    flag[0] = (g[0] == 0x3F803F80u) ? 1 : 0;   // bf16 ones pair vs fp32 one
}

// ---------- block reduce (sum of two values), 256 threads ----------
__device__ __forceinline__ void block_reduce2(float& s, float& s2, float* red, int tid) {
    int lane = tid & 63, wave = tid >> 6;
    #pragma unroll
    for (int m = 32; m >= 1; m >>= 1) { s += __shfl_xor(s, m); s2 += __shfl_xor(s2, m); }
    if (lane == 0) { red[wave] = s; red[4 + wave] = s2; }
    __syncthreads();
    s  = red[0] + red[1] + red[2] + red[3];
    s2 = red[4] + red[5] + red[6] + red[7];
}

// ---------- weight transpose+convert: in (K x N) -> out bf16 (N x K) ----------
__global__ __launch_bounds__(256) void transpose_k(const void* __restrict__ in,
                                                   u16* __restrict__ out, int K, int N,
                                                   long in_lstride, long out_lstride,
                                                   const int* __restrict__ fl) {
    __shared__ u16 tile[64][65];
    const int bf = fl[0];
    const size_t ioff = (size_t)blockIdx.z * (size_t)in_lstride;
    const size_t ooff = (size_t)blockIdx.z * (size_t)out_lstride;
    int k0 = blockIdx.y * 64, n0 = blockIdx.x * 64;
    int c = threadIdx.x & 63, r0 = threadIdx.x >> 6;
    #pragma unroll
    for (int r = r0; r < 64; r += 4) {
        size_t idx = ioff + (size_t)(k0 + r) * N + n0 + c;
        tile[r][c] = bf ? ((const u16*)in)[idx] : f2b(((const float*)in)[idx]);
    }
    __syncthreads();
    #pragma unroll
    for (int r = r0; r < 64; r += 4)
        out[ooff + (size_t)(n0 + r) * K + k0 + c] = tile[c][r];
}

// ---------- bias prep: convert all GEMM biases to bf16, qkv concatenated ----------
// layout: [0,13824) bqkv (6 x 2304) | [13824,18432) bo | [18432,36864) bf1 | [36864,41472) bf2
__global__ __launch_bounds__(256) void prep_bias(
    const void* __restrict__ bq, const void* __restrict__ bk, const void* __restrict__ bv,
    const void* __restrict__ bo, const void* __restrict__ bf1, const void* __restrict__ bf2,
    u16* __restrict__ out, const int* __restrict__ fl) {
    const int bf = fl[0];
    int i = blockIdx.x * 256 + threadIdx.x;
    if (i >= 41472) return;
    float v;
    if (i < 13824) {
        int l = i / 2304, c = i % 2304;
        v = (c < 768) ? lda(bq, (size_t)l * 768 + c, bf)
          : (c < 1536) ? lda(bk, (size_t)l * 768 + c - 768, bf)
                       : lda(bv, (size_t)l * 768 + c - 1536, bf);
    } else if (i < 18432) v = lda(bo,  i - 13824, bf);
    else if (i < 36864)   v = lda(bf1, i - 18432, bf);
    else                  v = lda(bf2, i - 36864, bf);
    out[i] = f2b(v);
}

// ---------- embedding + LN + selection scale ----------
__global__ __launch_bounds__(256) void embed_kernel(
    const int* __restrict__ src, const int* __restrict__ seg, const int* __restrict__ tib,
    const void* __restrict__ we, const void* __restrict__ pe, const void* __restrict__ se,
    const void* __restrict__ g, const void* __restrict__ bb, const void* __restrict__ sf,
    float* __restrict__ x32, u16* __restrict__ xb, const int* __restrict__ fl) {
    __shared__ float red[8];
    const int bf = fl[0];
    const int r = blockIdx.x, tid = threadIdx.x;
    const int s = r & (S_ - 1);
    const int w = src[r], sg = seg[r];
    const float scale = lda(sf, tib[r], bf);
    float v[3]; int col[3];
    #pragma unroll
    for (int i = 0; i < 3; ++i) {
        col[i] = tid + i * 256;
        v[i] = lda(we, (size_t)w * H_ + col[i], bf) + lda(pe, (size_t)s * H_ + col[i], bf)
             + lda(se, (size_t)sg * H_ + col[i], bf);
    }
    float su = v[0] + v[1] + v[2];
    float sq = v[0]*v[0] + v[1]*v[1] + v[2]*v[2];
    block_reduce2(su, sq, red, tid);
    const float mean = su * (1.0f / H_);
    const float var  = sq * (1.0f / H_) - mean * mean;
    const float inv  = rsqrtf(var + 1e-5f);
    #pragma unroll
    for (int i = 0; i < 3; ++i) {
        float y = ((v[i] - mean) * inv * lda(g, col[i], bf) + lda(bb, col[i], bf)) * scale;
        x32[(size_t)r * H_ + col[i]] = y;
        xb [(size_t)r * H_ + col[i]] = f2b(y);
    }
}

// ---------- residual add + LN (x32 master, bf16 shadow out) ----------
__global__ __launch_bounds__(256) void add_ln_kernel(
    const float* __restrict__ xin, const u16* __restrict__ t,
    const void* __restrict__ g, const void* __restrict__ bb, long goff,
    float* __restrict__ xout, u16* __restrict__ xb, const int* __restrict__ fl) {
    __shared__ float red[8];
    const int bf = fl[0];
    const int r = blockIdx.x, tid = threadIdx.x;
    const size_t rb = (size_t)r * H_;
    float v[3]; int col[3];
    #pragma unroll
    for (int i = 0; i < 3; ++i) {
        col[i] = tid + i * 256;
        v[i] = xin[rb + col[i]] + b2f(t[rb + col[i]]);
    }
    float su = v[0] + v[1] + v[2];
    float sq = v[0]*v[0] + v[1]*v[1] + v[2]*v[2];
    block_reduce2(su, sq, red, tid);
    const float mean = su * (1.0f / H_);
    const float var  = sq * (1.0f / H_) - mean * mean;
    const float inv  = rsqrtf(var + 1e-5f);
    #pragma unroll
    for (int i = 0; i < 3; ++i) {
        float y = (v[i] - mean) * inv * lda(g, goff + col[i], bf) + lda(bb, goff + col[i], bf);
        xout[rb + col[i]] = y;
        xb  [rb + col[i]] = f2b(y);
    }
}

// ---------- MFMA GEMM (m97-style async staging): C[M,N] = A * Bt^T + bias ----------
__global__ __launch_bounds__(256) void gemm_bt(
    const u16* __restrict__ A, const u16* __restrict__ Bt, const u16* __restrict__ bias,
    u16* __restrict__ C, int M, int N, int K, int act) {
    __shared__ alignas(16) u16 As[128 * 32];
    __shared__ alignas(16) u16 Bs[128 * 32];
    const int tid = threadIdx.x;
    const int bm = blockIdx.y * 128, bn = blockIdx.x * 128;
    const int wave = tid >> 6, lane = tid & 63;
    const int wm = (wave >> 1) * 64, wn = (wave & 1) * 64;
    const int qd = lane >> 4, l16 = lane & 15;

    const f32x4 fz = {0.f, 0.f, 0.f, 0.f};
    f32x4 acc[4][4];
    #pragma unroll
    for (int i = 0; i < 4; ++i)
        #pragma unroll
        for (int j = 0; j < 4; ++j) acc[i][j] = fz;

    const int c0 = tid, c1 = tid + 256;
    const int r0 = c0 >> 2, cc0 = (c0 & 3) * 8;
    const int r1 = c1 >> 2, cc1 = (c1 & 3) * 8;
    const u16* A0 = A  + (size_t)(bm + r0) * K + cc0;
    const u16* A1 = A  + (size_t)(bm + r1) * K + cc1;
    const u16* B0 = Bt + (size_t)(bn + r0) * K + cc0;
    const u16* B1 = Bt + (size_t)(bn + r1) * K + cc1;

    for (int k0 = 0; k0 < K; k0 += 32) {
        __syncthreads();               // prev iter's LDS reads complete
        async_lds16(A0 + k0, As + c0 * 8);
        async_lds16(A1 + k0, As + c1 * 8);
        async_lds16(B0 + k0, Bs + c0 * 8);
        async_lds16(B1 + k0, Bs + c1 * 8);
        __syncthreads();               // vmcnt drained by barrier semantics
        bf16x8 af[4], bfv[4];
        #pragma unroll
        for (int i = 0; i < 4; ++i)
            af[i] = *(const bf16x8*)(As + (wm + i * 16 + l16) * 32 + qd * 8);
        #pragma unroll
        for (int j = 0; j < 4; ++j)
            bfv[j] = *(const bf16x8*)(Bs + (wn + j * 16 + l16) * 32 + qd * 8);
        #pragma unroll
        for (int i = 0; i < 4; ++i)
            #pragma unroll
            for (int j = 0; j < 4; ++j)
                acc[i][j] = __builtin_amdgcn_mfma_f32_16x16x32_bf16(af[i], bfv[j], acc[i][j], 0, 0, 0);
    }

    // epilogue: C/D layout col=lane&15, row=(lane>>4)*4+reg
    #pragma unroll
    for (int i = 0; i < 4; ++i) {
        const int row0 = bm + wm + i * 16 + qd * 4;
        #pragma unroll
        for (int j = 0; j < 4; ++j) {
            const int col = bn + wn + j * 16 + l16;
            const float bv = b2f(bias[col]);
            #pragma unroll
            for (int r = 0; r < 4; ++r) {
                float v = acc[i][j][r] + bv;
                if (act == 1) v = gelu_tanh(v);
                C[(size_t)(row0 + r) * N + col] = f2b(v);
            }
        }
    }
}

// ---------- flash attention: 64 queries/block, online softmax, MFMA QK^T and PV ----------
__global__ __launch_bounds__(256) void attn_kernel(
    const u16* __restrict__ QKV, const int* __restrict__ seg, u16* __restrict__ Cb) {
    __shared__ alignas(16) u16 Qs[64 * 72];     // [q][d]
    __shared__ alignas(16) u16 Ks[128 * 72];    // [key][d]
    __shared__ alignas(16) u16 Vt[64 * 136];    // [d][key] with 16B-block xor swizzle
    __shared__ alignas(16) u16 Ps[64 * 136];    // [q][key]
    __shared__ float biasv[512];
    const int tid = threadIdx.x;
    const int qt = blockIdx.x, h = blockIdx.y, b = blockIdx.z;
    const int wave = tid >> 6, lane = tid & 63;
    const int qd = lane >> 4, l16 = lane & 15;
    const u16* Qg = QKV + (size_t)b * S_ * STRQ + h * 64;
    const u16* Kg = Qg + 768;
    const u16* Vg = Qg + 1536;

    for (int i = tid; i < 512; i += 256)
        biasv[i] = (seg[b * S_ + i] > 0) ? 0.0f : -1e9f;

    {   // stage Q tile 64x64 = 512 uint4 items
        int c = tid;
        #pragma unroll
        for (int u = 0; u < 2; ++u, c += 256) {
            int r = c >> 3, c8 = (c & 7) * 8;
            uint4 v4 = *(const uint4*)(Qg + (size_t)(qt * 64 + r) * STRQ + c8);
            *(uint4*)(Qs + r * 72 + c8) = v4;
        }
    }

    float m_run[4], l_run[4];
    f32x4 accO[4];
    #pragma unroll
    for (int r = 0; r < 4; ++r) { m_run[r] = -3.0e38f; l_run[r] = 0.f; }
    #pragma unroll
    for (int dt = 0; dt < 4; ++dt) accO[dt] = {0.f, 0.f, 0.f, 0.f};

    for (int kt = 0; kt < 512; kt += 128) {
        __syncthreads();                       // prev iter's Ks/Vt reads complete
        {   // stage K tile 128x64 = 1024 uint4 items
            int c = tid;
            #pragma unroll
            for (int u = 0; u < 4; ++u, c += 256) {
                int r = c >> 3, c8 = (c & 7) * 8;
                uint4 v4 = *(const uint4*)(Kg + (size_t)(kt + r) * STRQ + c8);
                *(uint4*)(Ks + r * 72 + c8) = v4;
            }
        }
        {   // stage V tile transposed: Vt[d][key], key-block xor-swizzled (1024 items)
            int c = tid;
            #pragma unroll
            for (int u = 0; u < 4; ++u, c += 256) {
                int r = c >> 3, d8 = (c & 7) * 8;
                uint4 v4 = *(const uint4*)(Vg + (size_t)(kt + r) * STRQ + d8);
                u16 tmp[8]; *(uint4*)tmp = v4;
                #pragma unroll
                for (int j = 0; j < 8; ++j) {
                    int d = d8 + j;
                    int blk = (r >> 3) ^ (d >> 3);
                    Vt[d * 136 + blk * 8 + (r & 7)] = tmp[j];
                }
            }
        }
        __syncthreads();

        // ---- QK^T: wave owns q rows wave*16..+15, all 128 keys ----
        f32x4 s[8];
        {
            bf16x8 aq[2];
            #pragma unroll
            for (int kd = 0; kd < 2; ++kd)
                aq[kd] = *(const bf16x8*)(Qs + (wave * 16 + l16) * 72 + kd * 32 + qd * 8);
            #pragma unroll
            for (int nt = 0; nt < 8; ++nt) {
                s[nt] = {0.f, 0.f, 0.f, 0.f};
                #pragma unroll
                for (int kd = 0; kd < 2; ++kd) {
                    bf16x8 bk = *(const bf16x8*)(Ks + (nt * 16 + l16) * 72 + kd * 32 + qd * 8);
                    s[nt] = __builtin_amdgcn_mfma_f32_16x16x32_bf16(aq[kd], bk, s[nt], 0, 0, 0);
                }
            }
        }
        // scale + mask bias (bias depends on key = col = nt*16+l16)
        #pragma unroll
        for (int nt = 0; nt < 8; ++nt) {
            const float bv = biasv[kt + nt * 16 + l16];
            #pragma unroll
            for (int r = 0; r < 4; ++r) s[nt][r] = s[nt][r] * 0.125f + bv;
        }
        // online softmax: rows live in (qd, r); reduce across 16 l16 lanes
        float alpha[4], rsum[4];
        #pragma unroll
        for (int r = 0; r < 4; ++r) {
            float m = s[0][r];
            #pragma unroll
            for (int nt = 1; nt < 8; ++nt) m = fmaxf(m, s[nt][r]);
            #pragma unroll
            for (int msk = 8; msk >= 1; msk >>= 1) m = fmaxf(m, __shfl_xor(m, msk));
            float mn = fmaxf(m_run[r], m);
            alpha[r] = __expf(m_run[r] - mn);
            m_run[r] = mn;
            rsum[r] = 0.f;
        }
        #pragma unroll
        for (int nt = 0; nt < 8; ++nt)
            #pragma unroll
            for (int r = 0; r < 4; ++r) {
                float p = __expf(s[nt][r] - m_run[r]);
                rsum[r] += p;
                Ps[(wave * 16 + qd * 4 + r) * 136 + nt * 16 + l16] = f2b(p);
            }
        #pragma unroll
        for (int r = 0; r < 4; ++r) {
            float t = rsum[r];
            #pragma unroll
            for (int msk = 8; msk >= 1; msk >>= 1) t += __shfl_xor(t, msk);
            l_run[r] = l_run[r] * alpha[r] + t;
        }
        #pragma unroll
        for (int dt = 0; dt < 4; ++dt)
            #pragma unroll
            for (int r = 0; r < 4; ++r) accO[dt][r] *= alpha[r];
        __syncthreads();                       // Ps visible (and Vt already staged)

        // ---- PV: O(16x64) += P(16x128) @ V(128x64) ----
        #pragma unroll
        for (int kk = 0; kk < 4; ++kk) {
            bf16x8 ap = *(const bf16x8*)(Ps + (wave * 16 + l16) * 136 + kk * 32 + qd * 8);
            #pragma unroll
            for (int dt = 0; dt < 4; ++dt) {
                const int d = dt * 16 + l16;
                const int blk = (kk * 4 + qd) ^ (d >> 3);
                bf16x8 bv = *(const bf16x8*)(Vt + d * 136 + blk * 8);
                accO[dt] = __builtin_amdgcn_mfma_f32_16x16x32_bf16(ap, bv, accO[dt], 0, 0, 0);
            }
        }
    }

    // epilogue: normalize and write ctx [row][h*64+d]
    #pragma unroll
    for (int r = 0; r < 4; ++r) {
        const int row = qt * 64 + wave * 16 + qd * 4 + r;
        const float inv = 1.0f / l_run[r];
        const size_t obase = ((size_t)b * S_ + row) * H_ + h * 64;
        #pragma unroll
        for (int dt = 0; dt < 4; ++dt)
            Cb[obase + dt * 16 + l16] = f2b(accO[dt][r] * inv);
    }
}

// ---------- head1: hid = tanh(pooled @ Wp1 + bp1) via MFMA, one wave per 16x16 tile ----------
// grid = 12 blocks x 256 threads; wave w handles j-tile (blockIdx.x*4+w)*16
__global__ __launch_bounds__(256) void head1_kernel(
    const u16* __restrict__ xb, const u16* __restrict__ Wp1T,
    const void* __restrict__ bp1, u16* __restrict__ hidb, const int* __restrict__ fl) {
    __shared__ alignas(16) u16 Xs[16 * 776];     // stride 776 breaks 16-way bank alias
    const int bf = fl[0];
    const int tid = threadIdx.x, wave = tid >> 6, lane = tid & 63;
    const int qd = lane >> 4, l16 = lane & 15;
    for (int i = tid; i < 16 * 96; i += 256) {   // 96 uint4 per pooled row
        int b = i / 96, c = (i % 96) * 8;
        *(uint4*)(Xs + b * 776 + c) = *(const uint4*)(xb + ((size_t)b * S_) * H_ + c);
    }
    __syncthreads();
    const int n0 = (blockIdx.x * 4 + wave) * 16;
    f32x4 acc = {0.f, 0.f, 0.f, 0.f};
    for (int k0 = 0; k0 < H_; k0 += 32) {
        bf16x8 a  = *(const bf16x8*)(Xs + l16 * 776 + k0 + qd * 8);
        bf16x8 bb = *(const bf16x8*)(Wp1T + (size_t)(n0 + l16) * H_ + k0 + qd * 8);
        acc = __builtin_amdgcn_mfma_f32_16x16x32_bf16(a, bb, acc, 0, 0, 0);
    }
    // C/D: col=l16 (j), row=qd*4+r (batch)
    #pragma unroll
    for (int r = 0; r < 4; ++r) {
        const int b = qd * 4 + r, j = n0 + l16;
        hidb[b * H_ + j] = f2b(tanhf(acc[r] + lda(bp1, j, bf)));
    }
}

// ---------- head2: logits, wave per (batch, label) ----------
__global__ __launch_bounds__(640) void head2_kernel(
    const u16* __restrict__ hidb, const void* __restrict__ Wp2, const void* __restrict__ bp2,
    float* __restrict__ lg, const int* __restrict__ fl) {
    const int bf = fl[0];
    const int b = blockIdx.x, j = threadIdx.x >> 6, lane = threadIdx.x & 63;
    float s = 0.f;
    for (int k = lane; k < H_; k += 64)
        s += b2f(hidb[b * H_ + k]) * lda(Wp2, (size_t)k * LAB_ + j, bf);
    #pragma unroll
    for (int m = 32; m >= 1; m >>= 1) s += __shfl_xor(s, m);
    if (lane == 0) lg[b * LAB_ + j] = s + lda(bp2, j, bf);
}

// ---------- head3: log-softmax loss + dual-format output ----------
__global__ __launch_bounds__(192) void head3_kernel(
    const float* __restrict__ lg, const int* __restrict__ tgt,
    void* __restrict__ outv, const int* __restrict__ fl) {
    __shared__ float lse[B_];
    const int bf = fl[0], t = threadIdx.x;
    if (t < B_) {
        float mx = -1e30f;
        for (int j = 0; j < LAB_; ++j) mx = fmaxf(mx, lg[t * LAB_ + j]);
        float s = 0.f;
        for (int j = 0; j < LAB_; ++j) s += expf(lg[t * LAB_ + j] - mx);
        lse[t] = mx + logf(s);
    }
    __syncthreads();
    float loss = 0.f;
    if (t == 0) {
        for (int b = 0; b < B_; ++b) loss += lse[b] - lg[b * LAB_ + tgt[b]];
        loss /= (float)B_;
    }
    if (bf) {
        u16* o = (u16*)outv;
        if (t == 0) o[0] = f2b(loss);
        if (t < B_ * LAB_) o[1 + t] = f2b(lg[t]);
    } else {
        float* o = (float*)outv;
        if (t == 0) o[0] = loss;
        if (t < B_ * LAB_) o[1 + t] = lg[t];
    }
}

// ---------- launch ----------
extern "C" void kernel_launch(void* const* d_in, const int* in_sizes, int n_in,
                              void* d_out, int out_size, void* d_ws, size_t ws_size,
                              hipStream_t stream) {
    (void)in_sizes; (void)n_in; (void)out_size; (void)ws_size;
    const int* src = (const int*)d_in[0];
    const int* seg = (const int*)d_in[1];
    const int* tgt = (const int*)d_in[2];
    const int* tib = (const int*)d_in[3];
    const void* we  = d_in[4];
    const void* pe  = d_in[5];
    const void* se  = d_in[6];
    const void* elg = d_in[7];
    const void* elb = d_in[8];
    const void* Wq  = d_in[9];
    const void* bq  = d_in[10];
    const void* Wk  = d_in[11];
    const void* bk  = d_in[12];
    const void* Wv  = d_in[13];
    const void* bv  = d_in[14];
    const void* Wo  = d_in[15];
    const void* bo  = d_in[16];
    const void* l1g = d_in[17];
    const void* l1b = d_in[18];
    const void* Wf1 = d_in[19];
    const void* bf1 = d_in[20];
    const void* Wf2 = d_in[21];
    const void* bf2 = d_in[22];
    const void* l2g = d_in[23];
    const void* l2b = d_in[24];
    const void* Wp1 = d_in[25];
    const void* bp1 = d_in[26];
    const void* Wp2 = d_in[27];
    const void* bp2 = d_in[28];
    const void* sf  = d_in[29];

    const size_t HH   = (size_t)H_ * H_;        // 589824
    const size_t HFF  = (size_t)H_ * FF_;       // 2359296
    const size_t MH   = (size_t)M_ * H_;        // 6291456
    const size_t MQKV = (size_t)M_ * STRQ;      // 18874368
    const size_t MFF  = (size_t)M_ * FF_;       // 25165824
    const size_t QKVW = (size_t)STRQ * H_;      // 1769472 (per-layer merged weight)

    char* w = (char*)d_ws;
    int* dflag  = (int*)w;  w += 256;
    u16* bias_ws = (u16*)w; w += 41472 * 2;     // prep_bias layout
    u16* WqkvT = (u16*)w;  w += L_ * QKVW * 2;
    u16* WoT   = (u16*)w;  w += L_ * HH  * 2;
    u16* Wf1T  = (u16*)w;  w += L_ * HFF * 2;
    u16* Wf2T  = (u16*)w;  w += L_ * HFF * 2;
    u16* Wp1T  = (u16*)w;  w += HH * 2;
    float* x32 = (float*)w; w += MH * 4;
    u16* xb    = (u16*)w;  w += MH * 2;
    u16* qkvb  = (u16*)w;  w += MQKV * 2;
    u16* ctxb  = (u16*)w;  w += MH * 2;
    u16* tmpb  = (u16*)w;  w += MH * 2;
    u16* ffb   = (u16*)w;  w += MFF * 2;
    u16* hidb  = (u16*)w;  w += (size_t)B_ * H_ * 2;
    float* lg  = (float*)w; w += (size_t)B_ * LAB_ * 4;

    u16* bqkv = bias_ws;            // 6 x 2304
    u16* bo6  = bias_ws + 13824;    // 6 x 768
    u16* bf16_= bias_ws + 18432;    // 6 x 3072
    u16* bf26 = bias_ws + 36864;    // 6 x 768

    const dim3 tb(256);
    detect_kernel<<<1, 1, 0, stream>>>((const u32*)elg, dflag);
    prep_bias<<<162, tb, 0, stream>>>(bq, bk, bv, bo, bf1, bf2, bias_ws, dflag);

    // weight transposes+convert; Wq/Wk/Wv interleave into per-layer 2304x768 blocks
    transpose_k<<<dim3(12, 12, 6), tb, 0, stream>>>(Wq, WqkvT,                    H_, H_, (long)HH, (long)QKVW, dflag);
    transpose_k<<<dim3(12, 12, 6), tb, 0, stream>>>(Wk, WqkvT + (size_t)768*768,  H_, H_, (long)HH, (long)QKVW, dflag);
    transpose_k<<<dim3(12, 12, 6), tb, 0, stream>>>(Wv, WqkvT + (size_t)1536*768, H_, H_, (long)HH, (long)QKVW, dflag);
    transpose_k<<<dim3(12, 12, 6), tb, 0, stream>>>(Wo,  WoT,  H_, H_,  (long)HH,  (long)HH,  dflag);
    transpose_k<<<dim3(48, 12, 6), tb, 0, stream>>>(Wf1, Wf1T, H_, FF_, (long)HFF, (long)HFF, dflag);
    transpose_k<<<dim3(12, 48, 6), tb, 0, stream>>>(Wf2, Wf2T, FF_, H_, (long)HFF, (long)HFF, dflag);
    transpose_k<<<dim3(12, 12, 1), tb, 0, stream>>>(Wp1, Wp1T, H_, H_,  (long)HH,  (long)HH,  dflag);

    embed_kernel<<<M_, tb, 0, stream>>>(src, seg, tib, we, pe, se, elg, elb, sf, x32, xb, dflag);

    for (int l = 0; l < L_; ++l) {
        gemm_bt<<<dim3(STRQ / 128, M_ / 128), tb, 0, stream>>>(xb, WqkvT + l * QKVW, bqkv + l * STRQ, qkvb, M_, STRQ, H_, 0);
        attn_kernel<<<dim3(S_ / 64, NH_, B_), tb, 0, stream>>>(qkvb, seg, ctxb);
        gemm_bt<<<dim3(H_ / 128, M_ / 128), tb, 0, stream>>>(ctxb, WoT + l * HH, bo6 + l * H_, tmpb, M_, H_, H_, 0);
        add_ln_kernel<<<M_, tb, 0, stream>>>(x32, tmpb, l1g, l1b, (long)l * H_, x32, xb, dflag);
        gemm_bt<<<dim3(FF_ / 128, M_ / 128), tb, 0, stream>>>(xb, Wf1T + l * HFF, bf16_ + l * FF_, ffb, M_, FF_, H_, 1);
        gemm_bt<<<dim3(H_ / 128, M_ / 128), tb, 0, stream>>>(ffb, Wf2T + l * HFF, bf26 + l * H_, tmpb, M_, H_, FF_, 0);
        add_ln_kernel<<<M_, tb, 0, stream>>>(x32, tmpb, l2g, l2b, (long)l * H_, x32, xb, dflag);
    }

    head1_kernel<<<12, tb, 0, stream>>>(xb, Wp1T, bp1, hidb, dflag);
    head2_kernel<<<B_, dim3(640), 0, stream>>>(hidb, Wp2, bp2, lg, dflag);
    head3_kernel<<<1, dim3(192), 0, stream>>>(lg, tgt, d_out, dflag);
}